// Round 1
// 351.464 us; speedup vs baseline: 1.0734x; 1.0734x over previous
//
#include <hip/hip_runtime.h>

#define NFEAT 128
#define NHID 64
#define NCLASS 40

#define BSH 8                    // bucket = 256 nodes
#define MAXBIN 512               // supports N <= 131072
#define CH 8192                  // edges per chunk in pass A

// ---------------- bf16 helpers (storage-only precision; compute is fp32) ----------------

__device__ __forceinline__ float bfu(unsigned short u) {
    return __uint_as_float((unsigned)u << 16);
}
__device__ __forceinline__ unsigned short fbf(float f) {
    unsigned u = __float_as_uint(f);
    u += 0x7fffu + ((u >> 16) & 1u);        // round-to-nearest-even
    return (unsigned short)(u >> 16);
}

// ======================= CSR build, hierarchical =======================

__launch_bounds__(256)
__global__ void binA1(const int* __restrict__ dst, int* __restrict__ gcount, int E, int nbin) {
    __shared__ int h[MAXBIN];
    const int t = threadIdx.x;
    for (int i = t; i < nbin; i += 256) h[i] = 0;
    __syncthreads();
    const int e0 = blockIdx.x * CH;
    const int e1 = min(e0 + CH, E);
    for (int i = e0 + t; i < e1; i += 256) atomicAdd(&h[dst[i] >> BSH], 1);
    __syncthreads();
    for (int i = t; i < nbin; i += 256) { int c = h[i]; if (c) atomicAdd(&gcount[i], c); }
}

__launch_bounds__(512)
__global__ void binscan(const int* __restrict__ gcount, int* __restrict__ gbase,
                        int* __restrict__ gcur, int* __restrict__ row_ptr,
                        int nbin, int N, int E) {
    __shared__ int sd[512];
    const int t = threadIdx.x;
    int v = (t < nbin) ? gcount[t] : 0;
    sd[t] = v;
    __syncthreads();
    for (int off = 1; off < 512; off <<= 1) {
        int tmp = (t >= off) ? sd[t - off] : 0;
        __syncthreads();
        sd[t] += tmp;
        __syncthreads();
    }
    int excl = sd[t] - v;
    if (t < nbin) { gbase[t] = excl; gcur[t] = excl; }
    if (t == 0) { gbase[nbin] = E; row_ptr[N] = E; }
}

__launch_bounds__(256)
__global__ void binA2(const int* __restrict__ src, const int* __restrict__ dst,
                      int* __restrict__ gcur, unsigned* __restrict__ ebuf, int E, int nbin) {
    __shared__ int h[MAXBIN];
    __shared__ int base[MAXBIN];
    const int t = threadIdx.x;
    for (int i = t; i < nbin; i += 256) h[i] = 0;
    __syncthreads();
    const int e0 = blockIdx.x * CH;
    const int e1 = min(e0 + CH, E);
    for (int i = e0 + t; i < e1; i += 256) atomicAdd(&h[dst[i] >> BSH], 1);
    __syncthreads();
    for (int i = t; i < nbin; i += 256) {
        int c = h[i];
        if (c) base[i] = atomicAdd(&gcur[i], c);
        h[i] = 0;                               // reuse as local cursor
    }
    __syncthreads();
    for (int i = e0 + t; i < e1; i += 256) {
        int d = dst[i];
        int b = d >> BSH;
        int pos = base[b] + atomicAdd(&h[b], 1);
        ebuf[pos] = ((unsigned)(d & ((1 << BSH) - 1)) << 24) | (unsigned)src[i];
    }
}

__launch_bounds__(256)
__global__ void binB(const unsigned* __restrict__ ebuf, const int* __restrict__ gbase,
                     int* __restrict__ row_ptr, float* __restrict__ dinv,
                     int* __restrict__ csr_src, int N) {
    __shared__ int cnt[256];
    __shared__ int sd[256];
    __shared__ int cur[256];
    const int b = blockIdx.x;
    const int n0 = b << BSH;
    const int t = threadIdx.x;
    const int b0 = gbase[b], b1 = gbase[b + 1];
    cnt[t] = 0;
    __syncthreads();
    for (int i = b0 + t; i < b1; i += 256) atomicAdd(&cnt[ebuf[i] >> 24], 1);
    __syncthreads();
    int v = cnt[t];
    sd[t] = v;
    __syncthreads();
    for (int off = 1; off < 256; off <<= 1) {
        int tmp = (t >= off) ? sd[t - off] : 0;
        __syncthreads();
        sd[t] += tmp;
        __syncthreads();
    }
    int excl = sd[t] - v;
    int n = n0 + t;
    if (n < N) {
        row_ptr[n] = b0 + excl;
        dinv[n] = rsqrtf((float)v + 1.0f);      // +1 self loop
    }
    cur[t] = b0 + excl;
    __syncthreads();
    for (int i = b0 + t; i < b1; i += 256) {
        unsigned p = ebuf[i];
        int pos = atomicAdd(&cur[p >> 24], 1);
        csr_src[pos] = (int)(p & 0xffffffu);
    }
}

// ======================= dense linear =======================
// out[n,:] = bf16( dinv[n] * (f(in[n,:]) @ W) ), f = relu(x + bias_prev) if RELU_BIAS.

template<int K, int F, bool RELU_BIAS, bool IN_BF16>
__launch_bounds__(256)
__global__ void lin_kernel(const void* __restrict__ in_, const float* __restrict__ W,
                           const float* __restrict__ bias, const float* __restrict__ dinv,
                           unsigned short* __restrict__ out, int N) {
    constexpr int FT = F / 4;
    constexpr int TG = 256 / FT;
    constexpr int NPT = 4;
    constexpr int NODES = TG * NPT;
    constexpr int KP = K + 4;

    __shared__ alignas(16) float Ws[K * F];
    __shared__ alignas(16) float xs[NODES * KP];

    const int tid = threadIdx.x;
    const int n0 = blockIdx.x * NODES;

    for (int q = tid; q < K * F / 4; q += 256)
        ((float4*)Ws)[q] = ((const float4*)W)[q];

    if constexpr (IN_BF16) {
        const unsigned short* in = (const unsigned short*)in_;
        for (int q = tid; q < NODES * (K / 8); q += 256) {
            int ni = q / (K / 8);
            int c = q - ni * (K / 8);
            int n = n0 + ni;
            float v[8];
            if (n < N) {
                uint4 raw = *(const uint4*)(in + (size_t)n * K + c * 8);
                unsigned rr[4] = {raw.x, raw.y, raw.z, raw.w};
                #pragma unroll
                for (int j = 0; j < 4; ++j) {
                    v[2 * j]     = __uint_as_float(rr[j] << 16);
                    v[2 * j + 1] = __uint_as_float(rr[j] & 0xffff0000u);
                }
            } else {
                #pragma unroll
                for (int j = 0; j < 8; ++j) v[j] = 0.f;
            }
            if constexpr (RELU_BIAS) {
                #pragma unroll
                for (int j = 0; j < 8; ++j) v[j] = fmaxf(v[j] + bias[c * 8 + j], 0.f);
            }
            *(float4*)&xs[ni * KP + c * 8]     = make_float4(v[0], v[1], v[2], v[3]);
            *(float4*)&xs[ni * KP + c * 8 + 4] = make_float4(v[4], v[5], v[6], v[7]);
        }
    } else {
        const float* in = (const float*)in_;
        for (int q = tid; q < NODES * (K / 4); q += 256) {
            int ni = q / (K / 4);
            int kq = q - ni * (K / 4);
            int n = n0 + ni;
            float4 v = make_float4(0.f, 0.f, 0.f, 0.f);
            if (n < N) v = ((const float4*)in)[(size_t)n * (K / 4) + kq];
            if constexpr (RELU_BIAS) {
                float4 b = ((const float4*)bias)[kq];
                v.x = fmaxf(v.x + b.x, 0.f);
                v.y = fmaxf(v.y + b.y, 0.f);
                v.z = fmaxf(v.z + b.z, 0.f);
                v.w = fmaxf(v.w + b.w, 0.f);
            }
            *(float4*)&xs[ni * KP + kq * 4] = v;
        }
    }
    __syncthreads();

    const int tx = tid % FT;
    const int tg = tid / FT;
    if (tg >= TG) return;

    float4 acc[NPT];
    #pragma unroll
    for (int i = 0; i < NPT; ++i) acc[i] = make_float4(0.f, 0.f, 0.f, 0.f);

    #pragma unroll 4
    for (int kq = 0; kq < K / 4; ++kq) {
        float4 w0 = *(const float4*)&Ws[(kq * 4 + 0) * F + tx * 4];
        float4 w1 = *(const float4*)&Ws[(kq * 4 + 1) * F + tx * 4];
        float4 w2 = *(const float4*)&Ws[(kq * 4 + 2) * F + tx * 4];
        float4 w3 = *(const float4*)&Ws[(kq * 4 + 3) * F + tx * 4];
        #pragma unroll
        for (int i = 0; i < NPT; ++i) {
            float4 xv = *(const float4*)&xs[(tg * NPT + i) * KP + kq * 4];
            acc[i].x += xv.x * w0.x + xv.y * w1.x + xv.z * w2.x + xv.w * w3.x;
            acc[i].y += xv.x * w0.y + xv.y * w1.y + xv.z * w2.y + xv.w * w3.y;
            acc[i].z += xv.x * w0.z + xv.y * w1.z + xv.z * w2.z + xv.w * w3.z;
            acc[i].w += xv.x * w0.w + xv.y * w1.w + xv.z * w2.w + xv.w * w3.w;
        }
    }

    #pragma unroll
    for (int i = 0; i < NPT; ++i) {
        int n = n0 + tg * NPT + i;
        if (n < N) {
            float d = dinv[n];
            ushort4 o;
            o.x = fbf(acc[i].x * d);
            o.y = fbf(acc[i].y * d);
            o.z = fbf(acc[i].z * d);
            o.w = fbf(acc[i].w * d);
            *(ushort4*)(out + (size_t)n * F + tx * 4) = o;
        }
    }
}

// ======================= gather aggregation, 16B-per-lane =======================
// One wave per node. 8 lanes per source row (lane loads uint4 = 8 bf16 features),
// so one load instruction fetches 8 edge rows (8 full 128B lines, all consumed).
// Edge slot = lane>>3; feature base = (lane&7)*8. Tail/missing edges resolve to a
// zeroed dummy row at index N (one broadcast L1-resident line). Slot partials are
// folded by a 3-stage shfl_xor once per node.
// RB variant (layer-2 output -> layer-3 input): writes bf16(dinv * relu(dinv*acc + bias)).

template<bool RB>
__launch_bounds__(256)
__global__ void gatherw(const unsigned short* __restrict__ g, const float* __restrict__ dinv,
                        const int* __restrict__ row_ptr, const int* __restrict__ csr_src,
                        const float* __restrict__ bias,
                        unsigned short* __restrict__ out, int N) {
    int gid = blockIdx.x * blockDim.x + threadIdx.x;
    int n = gid >> 6;
    int lane = threadIdx.x & 63;
    if (n >= N) return;
    const int lg = lane >> 3;           // edge slot 0..7
    const int fo = (lane & 7) << 3;     // feature base 0,8,..,56

    const int e0 = row_ptr[n], e1 = row_ptr[n + 1];

    float acc[8];
    #pragma unroll
    for (int j = 0; j < 8; ++j) acc[j] = 0.f;

    // prologue: batch A = {self, e0..e0+6}, batch B = {e0+7..e0+14}
    int ia = e0 + lg - 1;
    int sA = (lg == 0) ? n : ((ia < e1) ? csr_src[ia] : N);
    int ib = e0 + 7 + lg;
    int sB = (ib < e1) ? csr_src[ib] : N;
    int e = e0 + 15;

    for (;;) {
        uint4 rA = *(const uint4*)(g + (size_t)sA * 64 + fo);
        uint4 rB = *(const uint4*)(g + (size_t)sB * 64 + fo);
        bool more = (e < e1);
        if (more) {                               // prefetch next 16 edges' sources
            int iA = e + lg;
            int iB = e + 8 + lg;
            sA = (iA < e1) ? csr_src[iA] : N;
            sB = (iB < e1) ? csr_src[iB] : N;
        }
        unsigned ra[4] = {rA.x, rA.y, rA.z, rA.w};
        unsigned rb[4] = {rB.x, rB.y, rB.z, rB.w};
        #pragma unroll
        for (int j = 0; j < 4; ++j) {
            acc[2 * j]     += __uint_as_float(ra[j] << 16);
            acc[2 * j + 1] += __uint_as_float(ra[j] & 0xffff0000u);
            acc[2 * j]     += __uint_as_float(rb[j] << 16);
            acc[2 * j + 1] += __uint_as_float(rb[j] & 0xffff0000u);
        }
        if (!more) break;
        e += 16;
    }

    // fold the 8 edge slots: lanes with equal (lane&7) hold the same features
    #pragma unroll
    for (int j = 0; j < 8; ++j) {
        acc[j] += __shfl_xor(acc[j], 8);
        acc[j] += __shfl_xor(acc[j], 16);
        acc[j] += __shfl_xor(acc[j], 32);
    }

    if (lg == 0) {                               // 8 lanes write the full 128B row
        float d = dinv[n];
        unsigned short o[8];
        #pragma unroll
        for (int j = 0; j < 8; ++j) {
            float v;
            if constexpr (RB) v = d * fmaxf(d * acc[j] + bias[fo + j], 0.f);
            else              v = d * acc[j];
            o[j] = fbf(v);
        }
        *(uint4*)(out + (size_t)n * 64 + fo) = *(uint4*)o;
    }
}

// ======================= final dense: out = log_softmax(zagg @ W3 + b3) =======================
// W3 commuted past the aggregation: A(XW3) = (AX)W3, so the last gather runs on
// aligned 128B 64-wide rows and this kernel is a tiny dense epilogue.

__launch_bounds__(256)
__global__ void lsm40(const unsigned short* __restrict__ in, const float* __restrict__ W,
                      const float* __restrict__ b3, float* __restrict__ out, int N) {
    constexpr int K = NHID;          // 64
    constexpr int F = NCLASS;        // 40
    constexpr int FT = F / 4;        // 10
    constexpr int TG = 256 / FT;     // 25
    constexpr int NPT = 4;
    constexpr int NODES = TG * NPT;  // 100
    constexpr int KP = K + 4;        // 68
    constexpr int YS = F + 1;        // 41 (odd stride -> conflict-light LDS)

    __shared__ alignas(16) float Ws[K * F];
    __shared__ alignas(16) float xs[NODES * KP];
    __shared__ float mls[NODES];

    float* ys = xs;                  // reused after compute (NODES*YS <= NODES*KP)

    const int tid = threadIdx.x;
    const int n0 = blockIdx.x * NODES;

    for (int q = tid; q < K * F / 4; q += 256)
        ((float4*)Ws)[q] = ((const float4*)W)[q];

    for (int q = tid; q < NODES * (K / 8); q += 256) {
        int ni = q / (K / 8);
        int c = q - ni * (K / 8);
        int n = n0 + ni;
        float v[8];
        if (n < N) {
            uint4 raw = *(const uint4*)(in + (size_t)n * K + c * 8);
            unsigned rr[4] = {raw.x, raw.y, raw.z, raw.w};
            #pragma unroll
            for (int j = 0; j < 4; ++j) {
                v[2 * j]     = __uint_as_float(rr[j] << 16);
                v[2 * j + 1] = __uint_as_float(rr[j] & 0xffff0000u);
            }
        } else {
            #pragma unroll
            for (int j = 0; j < 8; ++j) v[j] = 0.f;
        }
        *(float4*)&xs[ni * KP + c * 8]     = make_float4(v[0], v[1], v[2], v[3]);
        *(float4*)&xs[ni * KP + c * 8 + 4] = make_float4(v[4], v[5], v[6], v[7]);
    }
    __syncthreads();

    const int tx = tid % FT;
    const int tg = tid / FT;

    float4 acc[NPT];
    #pragma unroll
    for (int i = 0; i < NPT; ++i) acc[i] = make_float4(0.f, 0.f, 0.f, 0.f);

    if (tg < TG) {
        #pragma unroll 4
        for (int kq = 0; kq < K / 4; ++kq) {
            float4 w0 = *(const float4*)&Ws[(kq * 4 + 0) * F + tx * 4];
            float4 w1 = *(const float4*)&Ws[(kq * 4 + 1) * F + tx * 4];
            float4 w2 = *(const float4*)&Ws[(kq * 4 + 2) * F + tx * 4];
            float4 w3 = *(const float4*)&Ws[(kq * 4 + 3) * F + tx * 4];
            #pragma unroll
            for (int i = 0; i < NPT; ++i) {
                float4 xv = *(const float4*)&xs[(tg * NPT + i) * KP + kq * 4];
                acc[i].x += xv.x * w0.x + xv.y * w1.x + xv.z * w2.x + xv.w * w3.x;
                acc[i].y += xv.x * w0.y + xv.y * w1.y + xv.z * w2.y + xv.w * w3.y;
                acc[i].z += xv.x * w0.z + xv.y * w1.z + xv.z * w2.z + xv.w * w3.z;
                acc[i].w += xv.x * w0.w + xv.y * w1.w + xv.z * w2.w + xv.w * w3.w;
            }
        }
    }
    __syncthreads();                 // xs reads done; safe to overwrite as ys

    if (tg < TG) {
        const float4 bb = *(const float4*)&b3[tx * 4];
        #pragma unroll
        for (int i = 0; i < NPT; ++i) {
            int node = tg * NPT + i;
            ys[node * YS + tx * 4 + 0] = acc[i].x + bb.x;
            ys[node * YS + tx * 4 + 1] = acc[i].y + bb.y;
            ys[node * YS + tx * 4 + 2] = acc[i].z + bb.z;
            ys[node * YS + tx * 4 + 3] = acc[i].w + bb.w;
        }
    }
    __syncthreads();

    if (tid < NODES) {
        float m = -1e30f;
        #pragma unroll 8
        for (int c = 0; c < F; ++c) m = fmaxf(m, ys[tid * YS + c]);
        float s = 0.f;
        #pragma unroll 8
        for (int c = 0; c < F; ++c) s += __expf(ys[tid * YS + c] - m);
        mls[tid] = m + __logf(s);
    }
    __syncthreads();

    const size_t ob = (size_t)n0 * F;
    for (int q = tid; q < NODES * F; q += 256) {
        int n = q / F;
        if (n0 + n < N) out[ob + q] = ys[n * YS + (q - n * F)] - mls[n];
    }
}

// ======================= launch =======================

extern "C" void kernel_launch(void* const* d_in, const int* in_sizes, int n_in,
                              void* d_out, int out_size, void* d_ws, size_t ws_size,
                              hipStream_t stream) {
    const float* x  = (const float*)d_in[0];
    const int*   ei = (const int*)  d_in[1];
    const float* W1 = (const float*)d_in[2];
    const float* b1 = (const float*)d_in[3];
    const float* W2 = (const float*)d_in[4];
    const float* b2 = (const float*)d_in[5];
    const float* W3 = (const float*)d_in[6];
    const float* b3 = (const float*)d_in[7];
    const int N = in_sizes[0] / NFEAT;
    const int E = in_sizes[1] / 2;
    const int* src = ei;
    const int* dst = ei + E;
    float* out = (float*)d_out;

    const int nbin = (N + (1 << BSH) - 1) >> BSH;          // 391 for N=100000

    // ---- workspace layout (4-byte units, 256-aligned sections) ----
    const size_t Np = ((size_t)N + 256) & ~(size_t)255;
    const size_t Ep = ((size_t)E + 255) & ~(size_t)255;
    const size_t Fp = (((size_t)N * 32 + 64) + 255) & ~(size_t)255;  // +1 zero row
    float* base = (float*)d_ws;
    int*      gcount  = (int*)(base);                       // MAXBIN
    int*      gbase   = (int*)(base + MAXBIN);              // MAXBIN+1 (padded)
    int*      gcur    = (int*)(base + 2 * MAXBIN + 256);    // MAXBIN
    int*      row_ptr = (int*)(base + 3 * MAXBIN + 256);    // Np
    float*    dinv    =        base + 3 * MAXBIN + 256 + Np;
    unsigned* ebuf    = (unsigned*)(base + 3 * MAXBIN + 256 + 2 * Np);
    int*      csr_src = (int*)(base + 3 * MAXBIN + 256 + 2 * Np + Ep);
    unsigned short* tb = (unsigned short*)(base + 3 * MAXBIN + 256 + 2 * Np + 2 * Ep);
    unsigned short* ab = (unsigned short*)(base + 3 * MAXBIN + 256 + 2 * Np + 2 * Ep + Fp);
    // total ~ 39 MB

    const int nchunk = (E + CH - 1) / CH;                   // 196

    // ---- CSR build (also produces dinv) ----
    hipMemsetAsync(gcount, 0, MAXBIN * sizeof(int), stream);
    // zero dummy row N of both feature buffers (gather tail slots read it)
    hipMemsetAsync(tb + (size_t)N * 64, 0, 64 * sizeof(unsigned short), stream);
    hipMemsetAsync(ab + (size_t)N * 64, 0, 64 * sizeof(unsigned short), stream);
    binA1<<<nchunk, 256, 0, stream>>>(dst, gcount, E, nbin);
    binscan<<<1, 512, 0, stream>>>(gcount, gbase, gcur, row_ptr, nbin, N, E);
    binA2<<<nchunk, 256, 0, stream>>>(src, dst, gcur, ebuf, E, nbin);
    binB<<<nbin, 256, 0, stream>>>(ebuf, gbase, row_ptr, dinv, csr_src, N);

    const int gatherBlocks = (int)(((size_t)N * 64 + 255) / 256);

    // ---- layer 1 ----
    lin_kernel<NFEAT, NHID, false, false><<<(N + 63) / 64, 256, 0, stream>>>(x, W1, nullptr, dinv, tb, N);
    gatherw<false><<<gatherBlocks, 256, 0, stream>>>(tb, dinv, row_ptr, csr_src, nullptr, ab, N);

    // ---- layer 2 ----
    lin_kernel<NHID, NHID, true, true><<<(N + 63) / 64, 256, 0, stream>>>(ab, W2, b1, dinv, tb, N);
    // aggregate + fused relu(.+b2)*dinv epilogue -> z (input to commuted layer 3)
    gatherw<true><<<gatherBlocks, 256, 0, stream>>>(tb, dinv, row_ptr, csr_src, b2, ab, N);

    // ---- layer 3 (W3 commuted past aggregation) ----
    gatherw<false><<<gatherBlocks, 256, 0, stream>>>(ab, dinv, row_ptr, csr_src, nullptr, tb, N);
    lsm40<<<(N + 99) / 100, 256, 0, stream>>>(tb, W3, b3, out, N);
}